// Round 1
// baseline (7609.948 us; speedup 1.0000x reference)
//
#include <hip/hip_runtime.h>
#include <hip/hip_fp16.h>

#define Bsz 64
#define Tlen 512
#define HD 512

typedef _Float16 h2v __attribute__((ext_vector_type(2)));

__device__ __forceinline__ float dot2acc(unsigned a, unsigned b, float c) {
#if __has_builtin(__builtin_amdgcn_fdot2)
    return __builtin_amdgcn_fdot2(__builtin_bit_cast(h2v, a),
                                  __builtin_bit_cast(h2v, b), c, false);
#else
    h2v xx = __builtin_bit_cast(h2v, a);
    h2v yy = __builtin_bit_cast(h2v, b);
    return c + (float)xx[0] * (float)yy[0] + (float)xx[1] * (float)yy[1];
#endif
}

// Packed f16 weight layout (per 512x512 matrix), uint4 units:
//   index = jblk*4096 + k8*64 + jin   (j = jblk*64 + jin = output row,
//                                      k8 = group of 8 input elems)
// Lane jin loads 16B; 64 lanes of a wave read a contiguous 1KB block.

__global__ __launch_bounds__(256) void pack_w(const float* __restrict__ Wih,
                                              const float* __restrict__ Whh,
                                              uint4* __restrict__ wp) {
    int tid = blockIdx.x * blockDim.x + threadIdx.x;  // 4 * 32768 total
    int m   = tid >> 15;
    int idx = tid & 32767;
    int jin = idx & 63;
    int k8  = (idx >> 6) & 63;
    int jblk = idx >> 12;
    int j = (jblk << 6) | jin;
    const float* W = (m == 0) ? Wih
                   : (m == 1) ? Whh
                   : (m == 2) ? (Wih + HD * HD)
                              : (Whh + HD * HD);
    const float* row = W + (size_t)j * HD + (k8 << 3);
    union { uint4 u; _Float16 h[8]; } v;
#pragma unroll
    for (int r = 0; r < 8; ++r) v.h[r] = (_Float16)row[r];
    wp[tid] = v.u;
}

__device__ __forceinline__ float matvec_acc(const uint4* __restrict__ Wp,
                                            const _Float16* hbuf,
                                            int jblk, int jin, float acc) {
    const uint4* p  = Wp + (jblk << 12) + jin;
    const uint4* hb = (const uint4*)hbuf;
#pragma unroll 4
    for (int k8 = 0; k8 < 64; ++k8) {
        uint4 w = p[k8 << 6];   // coalesced 16B/lane, stride 1KB/iter
        uint4 h = hb[k8];       // LDS broadcast (same addr all lanes)
        acc = dot2acc(w.x, h.x, acc);
        acc = dot2acc(w.y, h.y, acc);
        acc = dot2acc(w.z, h.z, acc);
        acc = dot2acc(w.w, h.w, acc);
    }
    return acc;
}

// One workgroup per batch element; persistent over all T steps.
// Thread j computes hidden unit j of each layer. State lives in LDS (f16).
__global__ __launch_bounds__(512) void rnn_chain(const float* __restrict__ x,
                                                 const float* __restrict__ h0in,
                                                 const float* __restrict__ bih,
                                                 const float* __restrict__ bhh,
                                                 const uint4* __restrict__ wp,
                                                 float* __restrict__ out) {
    __shared__ _Float16 xh[HD] __attribute__((aligned(16)));
    __shared__ _Float16 g0[HD] __attribute__((aligned(16)));
    __shared__ _Float16 g1[HD] __attribute__((aligned(16)));

    const uint4* Wih0p = wp;
    const uint4* Whh0p = wp + 32768;
    const uint4* Wih1p = wp + 65536;
    const uint4* Whh1p = wp + 98304;

    int b = blockIdx.x;
    int j = threadIdx.x;
    int jin  = j & 63;
    int jblk = j >> 6;

    float bias0 = bih[j] + bhh[j];
    float bias1 = bih[HD + j] + bhh[HD + j];

    g0[j] = (_Float16)h0in[(size_t)b * HD + j];
    g1[j] = (_Float16)h0in[(size_t)(Bsz + b) * HD + j];

    const float* xb = x + (size_t)b * Tlen * HD;
    float*       ob = out + (size_t)b * Tlen * HD;

    float xv = xb[j];
    float h0last = 0.f, h1last = 0.f;

    for (int t = 0; t < Tlen; ++t) {
        xh[j] = (_Float16)xv;
        __syncthreads();  // S1: xh, g0, g1 for this step visible
        float acc0 = bias0;
        acc0 = matvec_acc(Wih0p, xh, jblk, jin, acc0);
        acc0 = matvec_acc(Whh0p, g0, jblk, jin, acc0);
        float h0v = tanhf(acc0);
        if (t + 1 < Tlen) xv = xb[(size_t)(t + 1) * HD + j];  // prefetch
        __syncthreads();  // S2: all lanes done reading g0 (and xh)
        g0[j] = (_Float16)h0v;
        __syncthreads();  // S3: new g0 visible
        float acc1 = bias1;
        acc1 = matvec_acc(Wih1p, g0, jblk, jin, acc1);
        acc1 = matvec_acc(Whh1p, g1, jblk, jin, acc1);
        float h1v = tanhf(acc1);
        ob[(size_t)t * HD + j] = h1v;  // coalesced fp32 store
        __syncthreads();  // S4: all lanes done reading g1
        g1[j] = (_Float16)h1v;
        h0last = h0v;
        h1last = h1v;
    }

    float* hf = out + (size_t)Bsz * Tlen * HD;
    hf[(size_t)b * HD + j]         = h0last;
    hf[(size_t)(Bsz + b) * HD + j] = h1last;
}

extern "C" void kernel_launch(void* const* d_in, const int* in_sizes, int n_in,
                              void* d_out, int out_size, void* d_ws, size_t ws_size,
                              hipStream_t stream) {
    const float* x   = (const float*)d_in[0];
    const float* h0  = (const float*)d_in[1];
    const float* Wih = (const float*)d_in[2];
    const float* bih = (const float*)d_in[3];
    const float* Whh = (const float*)d_in[4];
    const float* bhh = (const float*)d_in[5];
    float* out = (float*)d_out;
    uint4* wp  = (uint4*)d_ws;  // 4 matrices * 512KB f16 = 2MB scratch

    pack_w<<<dim3(512), dim3(256), 0, stream>>>(Wih, Whh, wp);
    rnn_chain<<<dim3(Bsz), dim3(512), 0, stream>>>(x, h0, bih, bhh, wp, out);
}